// Round 1
// baseline (384.279 us; speedup 1.0000x reference)
//
#include <hip/hip_runtime.h>
#include <stdint.h>

typedef uint16_t u16;
typedef __bf16 bf16x8 __attribute__((ext_vector_type(8)));
typedef float f32x4 __attribute__((ext_vector_type(4)));

__device__ __forceinline__ u16 f2bf(float f) {
  union { float f; uint32_t u; } v; v.f = f;
  uint32_t u = v.u;
  u += 0x7FFFu + ((u >> 16) & 1u);   // round-to-nearest-even
  return (u16)(u >> 16);
}
__device__ __forceinline__ float bf2f(u16 h) {
  union { uint32_t u; float f; } v; v.u = ((uint32_t)h) << 16; return v.f;
}

// ---------------------------------------------------------------------------
// Both weight transposes in one launch (grid.z selects matrix).
// fp32 [R][C] -> bf16 [C][R]
// ---------------------------------------------------------------------------
__global__ void transpose_both(const float* __restrict__ w1, u16* __restrict__ w1t,
                               const float* __restrict__ w2, u16* __restrict__ w2t) {
  const float* in; u16* out; int R, C;
  if (blockIdx.z == 0) { in = w1; out = w1t; R = 1024; C = 512; }
  else {
    if (blockIdx.x >= 4 || blockIdx.y >= 16) return;   // block-uniform exit
    in = w2; out = w2t; R = 512; C = 128;
  }
  __shared__ float tile[32][33];
  int bx = blockIdx.x * 32, by = blockIdx.y * 32;
  int tx = threadIdx.x, ty = threadIdx.y;  // block (32,8)
  for (int i = 0; i < 32; i += 8)
    tile[ty + i][tx] = in[(size_t)(by + ty + i) * C + bx + tx];
  __syncthreads();
  for (int i = 0; i < 32; i += 8)
    out[(size_t)(bx + ty + i) * R + by + tx] = f2bf(tile[tx][ty + i]);
}

// ---------------------------------------------------------------------------
// Fused GEMM1 + PReLU + LayerNorm.
// x fp32 [8192][1024] (cast to bf16 in staging), w1t bf16 [512][1024],
// out = LN(PReLU(x@w1+b1)) bf16 [8192][512].
// Block: BM=32 rows x full N=512 cols, 256 threads = 4 waves; wave w owns
// cols [w*128, w*128+128) for ALL 32 rows -> LN reduces: in-register over j,
// xor-shuffle over the 16-lane col group, then a 4-wave LDS reduce.
// LDS: As 32x72 u16 (4.6 KB) + Bs 512x72 u16 (73.7 KB) = 78.3 KB.
// ---------------------------------------------------------------------------
#define G1_BK 64

__launch_bounds__(256)
__global__ void gemm1_ln_kernel(const float* __restrict__ A,
                                const u16* __restrict__ Bt,
                                const float* __restrict__ bias,
                                const float* __restrict__ prelu_a,
                                const float* __restrict__ gamma,
                                const float* __restrict__ beta,
                                u16* __restrict__ out) {
  const int K = 1024, N = 512;
  __shared__ u16 As[32][G1_BK + 8];    // row stride 144 B
  __shared__ u16 Bs[512][G1_BK + 8];
  const int lane = threadIdx.x & 63, wave = threadIdx.x >> 6;
  const int row0 = blockIdx.x * 32;

  f32x4 zero4 = {0.f, 0.f, 0.f, 0.f};
  f32x4 acc[2][8];
#pragma unroll
  for (int i = 0; i < 2; ++i)
#pragma unroll
    for (int j = 0; j < 8; ++j) acc[i][j] = zero4;

  const int r0 = threadIdx.x >> 3, kc0 = (threadIdx.x & 7) << 3;

  for (int k0 = 0; k0 < K; k0 += G1_BK) {
    // A stage: 32x64 u16, one 8-elem chunk per thread (fp32->bf16 cast).
    {
      const float4* p = (const float4*)(A + (size_t)(row0 + r0) * K + k0 + kc0);
      float4 f0 = p[0], f1 = p[1];
      u16 tmp[8] = {f2bf(f0.x), f2bf(f0.y), f2bf(f0.z), f2bf(f0.w),
                    f2bf(f1.x), f2bf(f1.y), f2bf(f1.z), f2bf(f1.w)};
      *(uint4*)(&As[r0][kc0]) = *(uint4*)tmp;
    }
    // B stage: full 512x64 u16 panel, 16 chunks per thread.
#pragma unroll
    for (int s = 0; s < 16; ++s) {
      int r = r0 + s * 32;
      *(uint4*)(&Bs[r][kc0]) = *(const uint4*)(Bt + (size_t)r * K + k0 + kc0);
    }
    __syncthreads();
#pragma unroll
    for (int kk = 0; kk < G1_BK; kk += 32) {
      bf16x8 a[2], b[8];
#pragma unroll
      for (int i = 0; i < 2; ++i)
        a[i] = *(const bf16x8*)(&As[i * 16 + (lane & 15)][kk + (lane >> 4) * 8]);
#pragma unroll
      for (int j = 0; j < 8; ++j)
        b[j] = *(const bf16x8*)(&Bs[wave * 128 + j * 16 + (lane & 15)][kk + (lane >> 4) * 8]);
#pragma unroll
      for (int i = 0; i < 2; ++i)
#pragma unroll
        for (int j = 0; j < 8; ++j)
          acc[i][j] = __builtin_amdgcn_mfma_f32_16x16x32_bf16(a[i], b[j], acc[i][j], 0, 0, 0);
    }
    __syncthreads();
  }

  // ---- epilogue: bias + PReLU in fp32 regs, then LN over the full row ----
  float ap = *prelu_a;
  float bcol[8], gcol[8], btc[8];
#pragma unroll
  for (int j = 0; j < 8; ++j) {
    int col = wave * 128 + j * 16 + (lane & 15);
    bcol[j] = bias[col]; gcol[j] = gamma[col]; btc[j] = beta[col];
  }

  float s1[2][4], s2[2][4];
#pragma unroll
  for (int i = 0; i < 2; ++i)
#pragma unroll
    for (int r = 0; r < 4; ++r) {
      float s = 0.f, q = 0.f;
#pragma unroll
      for (int j = 0; j < 8; ++j) {
        float v = acc[i][j][r] + bcol[j];
        v = v >= 0.f ? v : ap * v;
        acc[i][j][r] = v;
        s += v; q += v * v;
      }
      // reduce across the 16 lanes holding this row's 128-col slice
      s += __shfl_xor(s, 1); q += __shfl_xor(q, 1);
      s += __shfl_xor(s, 2); q += __shfl_xor(q, 2);
      s += __shfl_xor(s, 4); q += __shfl_xor(q, 4);
      s += __shfl_xor(s, 8); q += __shfl_xor(q, 8);
      s1[i][r] = s; s2[i][r] = q;
    }

  // cross-wave reduce via LDS (reuse As; all LDS reads done after final sync)
  float* red = (float*)&As[0][0];   // [32 rows][4 waves][2] = 1 KB
  if ((lane & 15) == 0) {
#pragma unroll
    for (int i = 0; i < 2; ++i)
#pragma unroll
      for (int r = 0; r < 4; ++r) {
        int row = i * 16 + (lane >> 4) * 4 + r;
        red[(row * 4 + wave) * 2 + 0] = s1[i][r];
        red[(row * 4 + wave) * 2 + 1] = s2[i][r];
      }
  }
  __syncthreads();

#pragma unroll
  for (int i = 0; i < 2; ++i)
#pragma unroll
    for (int r = 0; r < 4; ++r) {
      int row = i * 16 + (lane >> 4) * 4 + r;
      float S = 0.f, Q = 0.f;
#pragma unroll
      for (int w = 0; w < 4; ++w) {
        S += red[(row * 4 + w) * 2 + 0];
        Q += red[(row * 4 + w) * 2 + 1];
      }
      float mu = S * (1.f / 512.f);
      float var = Q * (1.f / 512.f) - mu * mu;
      float rstd = rsqrtf(var + 1e-6f);
#pragma unroll
      for (int j = 0; j < 8; ++j) {
        int col = wave * 128 + j * 16 + (lane & 15);
        out[(size_t)(row0 + row) * N + col] =
            f2bf((acc[i][j][r] - mu) * rstd * gcol[j] + btc[j]);
      }
    }
}

// ---------------------------------------------------------------------------
// GEMM2 + bias + row-normalize: z = hln @ w2 + b2 (fp32 -> d_out, NT store),
// zn = z / max(||z||,1e-8) (bf16 -> ws). BN=128 covers full out_dim.
// ---------------------------------------------------------------------------
#define BM 128
#define BN 128
#define BKT 64

__launch_bounds__(256)
__global__ void gemm2_kernel(const u16* __restrict__ A, const u16* __restrict__ Bt,
                             const float* __restrict__ bias,
                             float* __restrict__ z, u16* __restrict__ zn) {
  const int K = 512;
  __shared__ u16 As[BM][BKT + 8];
  __shared__ u16 Bs[BN][BKT + 8];
  const int lane = threadIdx.x & 63, wave = threadIdx.x >> 6;
  const int row0 = blockIdx.x * BM;

  f32x4 zero4 = {0.f, 0.f, 0.f, 0.f};
  f32x4 acc[2][8];
#pragma unroll
  for (int i = 0; i < 2; ++i)
#pragma unroll
    for (int j = 0; j < 8; ++j) acc[i][j] = zero4;

  const int r0 = threadIdx.x >> 3, kc0 = (threadIdx.x & 7) << 3;

  for (int k0 = 0; k0 < K; k0 += BKT) {
#pragma unroll
    for (int s = 0; s < 4; ++s) {
      int r = r0 + s * 32;
      *(uint4*)(&As[r][kc0]) = *(const uint4*)(A + (size_t)(row0 + r) * K + k0 + kc0);
      *(uint4*)(&Bs[r][kc0]) = *(const uint4*)(Bt + (size_t)r * K + k0 + kc0);
    }
    __syncthreads();
#pragma unroll
    for (int kk = 0; kk < BKT; kk += 32) {
      bf16x8 a[2], b[8];
#pragma unroll
      for (int i = 0; i < 2; ++i)
        a[i] = *(const bf16x8*)(&As[wave * 32 + i * 16 + (lane & 15)][kk + (lane >> 4) * 8]);
#pragma unroll
      for (int j = 0; j < 8; ++j)
        b[j] = *(const bf16x8*)(&Bs[j * 16 + (lane & 15)][kk + (lane >> 4) * 8]);
#pragma unroll
      for (int i = 0; i < 2; ++i)
#pragma unroll
        for (int j = 0; j < 8; ++j)
          acc[i][j] = __builtin_amdgcn_mfma_f32_16x16x32_bf16(a[i], b[j], acc[i][j], 0, 0, 0);
    }
    __syncthreads();
  }

#pragma unroll
  for (int i = 0; i < 2; ++i)
#pragma unroll
    for (int r = 0; r < 4; ++r) {
      int row = row0 + wave * 32 + i * 16 + (lane >> 4) * 4 + r;
      float vv[8], s = 0.f;
#pragma unroll
      for (int j = 0; j < 8; ++j) {
        int col = j * 16 + (lane & 15);
        float v = acc[i][j][r] + bias[col];
        vv[j] = v; s += v * v;
      }
      s += __shfl_xor(s, 1); s += __shfl_xor(s, 2);
      s += __shfl_xor(s, 4); s += __shfl_xor(s, 8);
      float inv = 1.f / fmaxf(sqrtf(s), 1e-8f);
#pragma unroll
      for (int j = 0; j < 8; ++j) {
        int col = j * 16 + (lane & 15);
        __builtin_nontemporal_store(vv[j], &z[(size_t)row * 128 + col]);
        zn[(size_t)row * 128 + col] = f2bf(vv[j] * inv);
      }
    }
}

// ---------------------------------------------------------------------------
// Gram: y = zn @ zn^T, zn bf16 [8192][128], y fp32 [8192][8192].
// K=128 fits LDS in ONE staging phase (69.6 KB): single barrier, no k0 loop.
// Output never re-read -> non-temporal stores (don't thrash L2's zn copy).
// ---------------------------------------------------------------------------
__launch_bounds__(256)
__global__ void gram_kernel(const u16* __restrict__ Z, float* __restrict__ y) {
  const int K = 128, Bdim = 8192;
  __shared__ u16 As[128][K + 8];   // row stride 272 B -> rows r, r+8 alias: 2-way, free
  __shared__ u16 Bs[128][K + 8];
  const int lane = threadIdx.x & 63, wave = threadIdx.x >> 6;
  const int row0 = blockIdx.x * 128, col0 = blockIdx.y * 128;

  f32x4 zero4 = {0.f, 0.f, 0.f, 0.f};
  f32x4 acc[2][8];
#pragma unroll
  for (int i = 0; i < 2; ++i)
#pragma unroll
    for (int j = 0; j < 8; ++j) acc[i][j] = zero4;

  const int r0 = threadIdx.x >> 4, kc0 = (threadIdx.x & 15) << 3;
#pragma unroll
  for (int s = 0; s < 8; ++s) {
    int r = r0 + s * 16;
    *(uint4*)(&As[r][kc0]) = *(const uint4*)(Z + (size_t)(row0 + r) * K + kc0);
    *(uint4*)(&Bs[r][kc0]) = *(const uint4*)(Z + (size_t)(col0 + r) * K + kc0);
  }
  __syncthreads();

#pragma unroll
  for (int kk = 0; kk < K; kk += 32) {
    bf16x8 a[2], b[8];
#pragma unroll
    for (int i = 0; i < 2; ++i)
      a[i] = *(const bf16x8*)(&As[wave * 32 + i * 16 + (lane & 15)][kk + (lane >> 4) * 8]);
#pragma unroll
    for (int j = 0; j < 8; ++j)
      b[j] = *(const bf16x8*)(&Bs[j * 16 + (lane & 15)][kk + (lane >> 4) * 8]);
#pragma unroll
    for (int i = 0; i < 2; ++i)
#pragma unroll
      for (int j = 0; j < 8; ++j)
        acc[i][j] = __builtin_amdgcn_mfma_f32_16x16x32_bf16(a[i], b[j], acc[i][j], 0, 0, 0);
  }

#pragma unroll
  for (int i = 0; i < 2; ++i)
#pragma unroll
    for (int r = 0; r < 4; ++r) {
      int row = row0 + wave * 32 + i * 16 + (lane >> 4) * 4 + r;
#pragma unroll
      for (int j = 0; j < 8; ++j) {
        int col = col0 + j * 16 + (lane & 15);
        __builtin_nontemporal_store(acc[i][j][r], &y[(size_t)row * Bdim + col]);
      }
    }
}

// ---------------------------------------------------------------------------
// Launch. Inputs: x, w1, b1, prelu_a, ln_gamma, ln_beta, w2, b2.
// d_out = [z (8192*128) | y_hat (8192*8192)] fp32.
// ws (bytes): w1t 1 MB @0, w2t 128 KB @1M, hln 8 MB, zn 2 MB.  (hact removed)
// ---------------------------------------------------------------------------
extern "C" void kernel_launch(void* const* d_in, const int* in_sizes, int n_in,
                              void* d_out, int out_size, void* d_ws, size_t ws_size,
                              hipStream_t stream) {
  const float* x       = (const float*)d_in[0];
  const float* w1      = (const float*)d_in[1];
  const float* b1      = (const float*)d_in[2];
  const float* prelu_a = (const float*)d_in[3];
  const float* gamma   = (const float*)d_in[4];
  const float* beta    = (const float*)d_in[5];
  const float* w2      = (const float*)d_in[6];
  const float* b2      = (const float*)d_in[7];

  float* z_out = (float*)d_out;
  float* yhat  = z_out + (size_t)8192 * 128;

  char* ws = (char*)d_ws;
  u16* w1t = (u16*)(ws);                                  // [512][1024]  1 MB
  u16* w2t = (u16*)(ws + (1u << 20));                     // [128][512]   128 KB
  u16* hln = (u16*)(ws + (1u << 20) + (1u << 17));        // [8192][512]  8 MB
  u16* zn  = (u16*)(ws + (1u << 20) + (1u << 17) + (8u << 20)); // [8192][128] 2 MB

  transpose_both<<<dim3(16, 32, 2), dim3(32, 8), 0, stream>>>(w1, w1t, w2, w2t);
  gemm1_ln_kernel<<<256, 256, 0, stream>>>(x, w1t, b1, prelu_a, gamma, beta, hln);
  gemm2_kernel<<<64, 256, 0, stream>>>(hln, w2t, b2, z_out, zn);
  gram_kernel<<<dim3(64, 64), 256, 0, stream>>>(zn, yhat);
}